// Round 13
// baseline (699.895 us; speedup 1.0000x reference)
//
#include <hip/hip_runtime.h>
#include <hip/hip_cooperative_groups.h>

namespace cg = cooperative_groups;

typedef unsigned short ushort_t;
typedef __attribute__((ext_vector_type(8))) short bf16x8;
typedef __attribute__((ext_vector_type(4))) float f32x4v;

#define BN 128        // nodes per bucket
#define LOGBN 7
#define CAP 3072      // LDS staging capacity in fine_sort (count ~2046 +- 45)
#define MAXBKT 1024   // LDS bound for hist/cursor arrays (nbkt = 782)
#define NB3 256       // edge partitions for hist/scatter (one-pass column scan)

static __device__ __forceinline__ ushort_t f2bf(float f) {
  union { float f; unsigned int i; } v; v.f = f;
  unsigned int r = v.i + 0x7FFFu + ((v.i >> 16) & 1u);
  return (ushort_t)(r >> 16);
}
static __device__ __forceinline__ float leaky(float s) {
  return s > 0.f ? s : 0.2f * s;
}

// ---------------------------------------------------------------------------
// One gat_linear unit (64 nodes) — byte-equivalent to R12's proven body.
// Leading __syncthreads protects the LDS union against the caller's prior use.
// ---------------------------------------------------------------------------
static __device__ void linear_unit(
    int b, const float* __restrict__ feat, const ushort_t* __restrict__ wfrag,
    ushort_t* __restrict__ h_out, float* __restrict__ el,
    float* __restrict__ er, float* __restrict__ blockmax2, int N,
    ushort_t* sFb, float* wmax)
{
  const int t = threadIdx.x;
  const int w = t >> 6, l = t & 63;
  const int q = l >> 4, m = l & 15;
  __syncthreads();
  const float4* gF = (const float4*)(feat + (size_t)b * 64 * 128);
  #pragma unroll
  for (int i = 0; i < 8; ++i) {
    const int idx = i * 256 + t;
    const int node = idx >> 5, off = idx & 31;
    float4 v = make_float4(0.f, 0.f, 0.f, 0.f);
    if (b * 64 + node < N) v = gF[idx];
    unsigned int p0 = ((unsigned int)f2bf(v.y) << 16) | f2bf(v.x);
    unsigned int p1 = ((unsigned int)f2bf(v.w) << 16) | f2bf(v.z);
    *(uint2*)(sFb + node * 136 + off * 4) = make_uint2(p0, p1);
  }
  __syncthreads();

  bf16x8 a[4];
  const ushort_t* arow = sFb + (w * 16 + m) * 136 + q * 8;
  #pragma unroll
  for (int kc = 0; kc < 4; ++kc)
    a[kc] = *(const bf16x8*)(arow + kc * 32);

  #pragma unroll
  for (int tile = 0; tile < 4; ++tile) {
    f32x4v acc = {0.f, 0.f, 0.f, 0.f};
    #pragma unroll
    for (int kc = 0; kc < 4; ++kc) {
      bf16x8 bfr = *(const bf16x8*)(wfrag + ((tile * 4 + kc) * 64 + l) * 8);
      acc = __builtin_amdgcn_mfma_f32_16x16x32_bf16(a[kc], bfr, acc, 0, 0, 0);
    }
    #pragma unroll
    for (int r = 0; r < 4; ++r) {
      const int gn = b * 64 + w * 16 + q * 4 + r;
      if (gn < N) h_out[(size_t)gn * 64 + tile * 16 + m] = f2bf(acc[r]);
    }
  }

  f32x4v acc4 = {0.f, 0.f, 0.f, 0.f};
  #pragma unroll
  for (int kc = 0; kc < 4; ++kc) {
    bf16x8 bfr = *(const bf16x8*)(wfrag + ((4 * 4 + kc) * 64 + l) * 8);
    acc4 = __builtin_amdgcn_mfma_f32_16x16x32_bf16(a[kc], bfr, acc4, 0, 0, 0);
  }
  float mel = -1e30f, mer = -1e30f;
  #pragma unroll
  for (int r = 0; r < 4; ++r) {
    const int gn = b * 64 + w * 16 + q * 4 + r;
    const float v = acc4[r];
    if (m < 4) {
      if (gn < N) el[gn * 4 + m] = v;
      mel = fmaxf(mel, v);
    } else if (m < 8) {
      if (gn < N) er[gn * 4 + (m - 4)] = v;
      mer = fmaxf(mer, v);
    }
  }
  #pragma unroll
  for (int o = 1; o <= 32; o <<= 1) {
    mel = fmaxf(mel, __shfl_xor(mel, o, 64));
    mer = fmaxf(mer, __shfl_xor(mer, o, 64));
  }
  if (l == 0) { wmax[w * 2] = mel; wmax[w * 2 + 1] = mer; }
  __syncthreads();
  if (t == 0) {
    float aa = fmaxf(fmaxf(wmax[0], wmax[2]), fmaxf(wmax[4], wmax[6]));
    float cc = fmaxf(fmaxf(wmax[1], wmax[3]), fmaxf(wmax[5], wmax[7]));
    blockmax2[b * 2] = aa;
    blockmax2[b * 2 + 1] = cc;
  }
}

// work-stealing pull: block-uniform unit index or -1 when exhausted
static __device__ int pull_unit(int* linCtr, int nbL, int* pick) {
  __syncthreads();
  if (threadIdx.x == 0) *pick = atomicAdd(linCtr, 1);
  __syncthreads();
  return (*pick < nbL) ? *pick : -1;
}

// ---------------------------------------------------------------------------
// Cooperative pre-pass: P0 hist(+Wpack) | P1 scan + linear | P2 scatter +
// linear-drain | P3 fine_sort + gmax. grid.sync() between phases. All phase
// bodies are R12's proven kernels; linear units are work-stolen to fill
// whatever the sort roles leave idle.
// ---------------------------------------------------------------------------
__global__ __launch_bounds__(256) void gat_pre(
    const float* __restrict__ W, const float* __restrict__ attnl,
    const float* __restrict__ attnr, ushort_t* __restrict__ wfrag,
    const int* __restrict__ src, const int* __restrict__ trg, int E,
    int nbkt, int* __restrict__ blockHist, int epb,
    const float* __restrict__ feat, ushort_t* __restrict__ h_bf,
    float* __restrict__ el, float* __restrict__ er,
    float* __restrict__ blockmax2, int N, int nbL,
    int* __restrict__ colTotal, int* __restrict__ bucketBase,
    unsigned int* __restrict__ binned,
    int* __restrict__ rowbeg, int* __restrict__ rowend,
    float* __restrict__ gmaxM, int* __restrict__ linCtr)
{
  cg::grid_group grid = cg::this_grid();
  const int gb = blockIdx.x;
  const int G  = gridDim.x;
  const int t  = threadIdx.x;
  const int l  = t & 63, w = t >> 6;

  __shared__ __align__(16) union {
    struct { ushort_t sFb[64 * 136]; float wmax[8]; } lin;   // 17.4 KB
    int hist[MAXBKT];                                        // 4 KB
    struct { int cur[MAXBKT]; int wt[4]; } sc;               // 4 KB
    struct { unsigned int pld[CAP]; int h[BN]; int c[BN]; int wtot[2]; } fs;
    float wmg[8];
  } u;
  __shared__ int pick;

  const int stride = G >> 8;   // G is a multiple of 256

  // ---------------- P0: histogram (strided roles) + W-pack ----------------
  const bool isHist = (gb % stride == 0) && (gb / stride < NB3);
  if (isHist) {
    const int hb = gb / stride;
    for (int i = t; i < nbkt; i += 256) u.hist[i] = 0;
    __syncthreads();
    const int s0 = hb * epb, e0 = min(s0 + epb, E);
    for (int e = s0 + t; e < e0; e += 256)
      atomicAdd(&u.hist[trg[e] >> LOGBN], 1);
    __syncthreads();
    for (int i = t; i < nbkt; i += 256) blockHist[hb * nbkt + i] = u.hist[i];
  }
  if (gb == G - 1) {
    // W_ext pack (R6 proven direct-load version; one block)
    const int kc = t >> 6;
    const int q = l >> 4, n = l & 15;
    #pragma unroll
    for (int tile = 0; tile < 5; ++tile) {
      #pragma unroll
      for (int j = 0; j < 8; ++j) {
        const int k = kc * 32 + q * 8 + j;
        float v = 0.f;
        if (tile < 4) {
          v = W[k * 64 + tile * 16 + n];
        } else if (n < 4) {
          for (int f = 0; f < 16; ++f)
            v += W[k * 64 + n * 16 + f] * attnl[n * 16 + f];
        } else if (n < 8) {
          const int hd = n - 4;
          for (int f = 0; f < 16; ++f)
            v += W[k * 64 + hd * 16 + f] * attnr[hd * 16 + f];
        }
        wfrag[((tile * 4 + kc) * 64 + l) * 8 + j] = f2bf(v);
      }
    }
  }
  __threadfence();
  grid.sync();

  // ---------------- P1: column scan + linear (quota 2) ----------------
  for (int sb = gb; sb < nbkt; sb += G) {
    const int v = blockHist[t * nbkt + sb];
    int incl = v;
    #pragma unroll
    for (int d = 1; d < 64; d <<= 1) {
      int uu = __shfl_up(incl, d, 64);
      if (l >= d) incl += uu;
    }
    if (l == 63) u.sc.wt[w] = incl;
    __syncthreads();
    int woff = 0;
    for (int k = 0; k < w; ++k) woff += u.sc.wt[k];
    blockHist[t * nbkt + sb] = woff + incl - v;
    if (t == 255) colTotal[sb] = woff + incl;
    __syncthreads();
  }
  #pragma unroll 1
  for (int qn = 0; qn < 2; ++qn) {
    const int un = pull_unit(linCtr, nbL, &pick);
    if (un < 0) break;
    linear_unit(un, feat, wfrag, h_bf, el, er, blockmax2, N,
                u.lin.sFb, u.lin.wmax);
  }
  __threadfence();
  grid.sync();

  // ---------------- P2: scatter (strided roles) + linear drain ----------------
  const bool isScat = (gb % stride == 0) && (gb / stride < NB3);
  if (isScat) {
    const int sb2 = gb / stride;
    int carry = 0;
    for (int ch = 0; ch * 256 < nbkt; ++ch) {
      const int i = ch * 256 + t;
      const int v = (i < nbkt) ? colTotal[i] : 0;
      int incl = v;
      #pragma unroll
      for (int d = 1; d < 64; d <<= 1) {
        int uu = __shfl_up(incl, d, 64);
        if (l >= d) incl += uu;
      }
      if (l == 63) u.sc.wt[w] = incl;
      __syncthreads();
      int woff = 0;
      for (int k = 0; k < w; ++k) woff += u.sc.wt[k];
      if (i < nbkt) u.sc.cur[i] = carry + woff + incl - v;
      carry += u.sc.wt[0] + u.sc.wt[1] + u.sc.wt[2] + u.sc.wt[3];
      __syncthreads();
    }
    if (gb == 0) {
      for (int i = t; i < nbkt; i += 256) bucketBase[i] = u.sc.cur[i];
      if (t == 0) bucketBase[nbkt] = carry;
    }
    for (int i = t; i < nbkt; i += 256) u.sc.cur[i] += blockHist[sb2 * nbkt + i];
    __syncthreads();
    const int s0 = sb2 * epb, e0 = min(s0 + epb, E);
    for (int e = s0 + t; e < e0; e += 256) {
      const int ti = trg[e];
      const int bkt = ti >> LOGBN;
      const int pos = atomicAdd(&u.sc.cur[bkt], 1);
      binned[pos] = ((unsigned int)src[e] << LOGBN) | (unsigned int)(ti & (BN - 1));
    }
  } else {
    #pragma unroll 1
    while (true) {
      const int un = pull_unit(linCtr, nbL, &pick);
      if (un < 0) break;
      linear_unit(un, feat, wfrag, h_bf, el, er, blockmax2, N,
                  u.lin.sFb, u.lin.wmax);
    }
  }
  __threadfence();
  grid.sync();

  // ---------------- P3: fine sort (looped) + gmax ----------------
  #pragma unroll 1
  for (int fb = gb; fb < nbkt; fb += G) {
    __syncthreads();
    const int base = bucketBase[fb];
    const int cn = min(bucketBase[fb + 1] - base, CAP);
    unsigned int* slot = binned + base;
    if (t < BN) u.fs.h[t] = 0;
    __syncthreads();
    for (int i = t; i < cn; i += 256) {
      const unsigned int pv = slot[i];
      u.fs.pld[i] = pv;
      atomicAdd(&u.fs.h[pv & (BN - 1)], 1);
    }
    __syncthreads();
    int v = 0, incl = 0;
    if (t < BN) {
      v = u.fs.h[t];
      incl = v;
      #pragma unroll
      for (int d = 1; d < 64; d <<= 1) {
        int uu = __shfl_up(incl, d, 64);
        if (l >= d) incl += uu;
      }
    }
    if (t < BN && l == 63) u.fs.wtot[t >> 6] = incl;
    __syncthreads();
    if (t < BN) {
      const int excl = incl - v + ((t >= 64) ? u.fs.wtot[0] : 0);
      u.fs.c[t] = excl;
      const int node = fb * BN + t;
      if (node < N) {
        rowbeg[node] = base + excl;
        rowend[node] = base + excl + v;
      }
    }
    __syncthreads();
    for (int i = t; i < cn; i += 256) {
      const unsigned int pv = u.fs.pld[i];
      const int pos = atomicAdd(&u.fs.c[pv & (BN - 1)], 1);
      slot[pos] = pv >> LOGBN;
    }
  }
  if (gb == G - 1) {
    __syncthreads();
    float mel = -1e30f, mer = -1e30f;
    for (int i = t; i < nbL; i += 256) {
      mel = fmaxf(mel, blockmax2[i * 2]);
      mer = fmaxf(mer, blockmax2[i * 2 + 1]);
    }
    #pragma unroll
    for (int o = 1; o <= 32; o <<= 1) {
      mel = fmaxf(mel, __shfl_xor(mel, o, 64));
      mer = fmaxf(mer, __shfl_xor(mer, o, 64));
    }
    if (l == 0) { u.wmg[w * 2] = mel; u.wmg[w * 2 + 1] = mer; }
    __syncthreads();
    if (t == 0) {
      float aa = fmaxf(fmaxf(u.wmg[0], u.wmg[2]), fmaxf(u.wmg[4], u.wmg[6]));
      float cc = fmaxf(fmaxf(u.wmg[1], u.wmg[3]), fmaxf(u.wmg[5], u.wmg[7]));
      gmaxM[0] = fmaxf(0.f, aa + cc);
    }
  }
}

// ---------------------------------------------------------------------------
// Aggregation (R12 proven, byte-identical): FOUR nodes per wave, batched
// gathers, rowbeg/rowend slotted CSR.
// ---------------------------------------------------------------------------
#define UNPACK_FMA(hv, p, acc) do { \
  union { unsigned int i; float f; } c_; \
  c_.i = (hv).x << 16;          acc[0] += c_.f * (p); \
  c_.i = (hv).x & 0xffff0000u;  acc[1] += c_.f * (p); \
  c_.i = (hv).y << 16;          acc[2] += c_.f * (p); \
  c_.i = (hv).y & 0xffff0000u;  acc[3] += c_.f * (p); \
  c_.i = (hv).z << 16;          acc[4] += c_.f * (p); \
  c_.i = (hv).z & 0xffff0000u;  acc[5] += c_.f * (p); \
  c_.i = (hv).w << 16;          acc[6] += c_.f * (p); \
  c_.i = (hv).w & 0xffff0000u;  acc[7] += c_.f * (p); \
} while (0)

#define LOADJ(j, hA_, hB_, qA_, qB_) do { \
  const int i_ = iA0 + (j) * 4; \
  const int sA_ = sSw[i_]; \
  const int sB_ = sSw[i_ + 32]; \
  qA_ = sPw[i_ * 4 + hd2]; \
  qB_ = sPw[(i_ + 32) * 4 + hd2]; \
  hA_ = *(const uint4*)(hcg + (size_t)sA_ * 64); \
  hB_ = *(const uint4*)(hcg + (size_t)sB_ * 64); \
} while (0)

__global__ __launch_bounds__(256) void gat_agg(
    const unsigned int* __restrict__ csrsrc, const int* __restrict__ rowbeg,
    const int* __restrict__ rowend,
    const float4* __restrict__ el4, const float4* __restrict__ er4,
    const ushort_t* __restrict__ hbf, const float* __restrict__ gmaxM,
    float* __restrict__ out, int N)
{
  __shared__ float sP[4 * 64 * 4];
  __shared__ int sS[4 * 64];
  const int t = threadIdx.x;
  const int l = t & 63;
  const int w = t >> 6;
  const int nbase = blockIdx.x * 16 + w * 4;
  const int rg = l >> 3;
  const int cg2 = l & 7;
  const int hd2 = cg2 >> 1;
  const int ks = l >> 4;
  const int le = l & 15;
  const float M = gmaxM[0];
  float* sPw = sP + w * 256;
  int* sSw = sS + w * 64;
  const ushort_t* hcg = hbf + cg2 * 8;
  const int iA0 = ((rg >> 2) * 16) + (rg & 3);

  const int nk = nbase + ks;
  int rs = 0, re = 0;
  if (nk < N) { rs = rowbeg[nk]; re = rowend[nk]; }
  const float4 ernk = (rs < re) ? er4[nk]
                                : make_float4(0.f, 0.f, 0.f, 0.f);
  int deg = re - rs;
  deg = max(deg, __shfl_xor(deg, 16, 64));
  deg = max(deg, __shfl_xor(deg, 32, 64));
  const int chunks = (deg + 15) >> 4;

  float aA[8] = {0.f,0.f,0.f,0.f,0.f,0.f,0.f,0.f};
  float aB[8] = {0.f,0.f,0.f,0.f,0.f,0.f,0.f,0.f};
  float dA = 0.f, dB = 0.f;

  for (int c = 0; c < chunks; ++c) {
    int sn = 0;
    float4 pv = make_float4(0.f, 0.f, 0.f, 0.f);
    const int ei = rs + c * 16 + le;
    if (ei < re) {
      sn = (int)csrsrc[ei];
      const float4 a = el4[sn];
      pv.x = __expf(leaky(a.x + ernk.x) - M);
      pv.y = __expf(leaky(a.y + ernk.y) - M);
      pv.z = __expf(leaky(a.z + ernk.z) - M);
      pv.w = __expf(leaky(a.w + ernk.w) - M);
    }
    *(float4*)(sPw + l * 4) = pv;
    sSw[l] = sn;

    const int rem = min(deg - c * 16, 16);
    const int jmax = (rem + 3) >> 2;
    uint4 h0A, h0B, h1A, h1B, h2A, h2B, h3A, h3B;
    float q0A, q0B, q1A, q1B, q2A, q2B, q3A, q3B;
    LOADJ(0, h0A, h0B, q0A, q0B);
    if (jmax > 1) LOADJ(1, h1A, h1B, q1A, q1B);
    if (jmax > 2) LOADJ(2, h2A, h2B, q2A, q2B);
    if (jmax > 3) LOADJ(3, h3A, h3B, q3A, q3B);

    UNPACK_FMA(h0A, q0A, aA); UNPACK_FMA(h0B, q0B, aB);
    dA += q0A; dB += q0B;
    if (jmax > 1) {
      UNPACK_FMA(h1A, q1A, aA); UNPACK_FMA(h1B, q1B, aB);
      dA += q1A; dB += q1B;
    }
    if (jmax > 2) {
      UNPACK_FMA(h2A, q2A, aA); UNPACK_FMA(h2B, q2B, aB);
      dA += q2A; dB += q2B;
    }
    if (jmax > 3) {
      UNPACK_FMA(h3A, q3A, aA); UNPACK_FMA(h3B, q3B, aB);
      dA += q3A; dB += q3B;
    }
  }

  #pragma unroll
  for (int o = 8; o <= 16; o <<= 1) {
    #pragma unroll
    for (int i = 0; i < 8; ++i) {
      aA[i] += __shfl_xor(aA[i], o, 64);
      aB[i] += __shfl_xor(aB[i], o, 64);
    }
    dA += __shfl_xor(dA, o, 64);
    dB += __shfl_xor(dB, o, 64);
  }
  if ((rg & 3) == 0) {
    const int nA = nbase + (rg >> 2);
    const int nB = nA + 2;
    const float rA = 1.0f / (dA + 1e-16f);
    const float rB = 1.0f / (dB + 1e-16f);
    if (nA < N) {
      float4* orow = (float4*)(out + (size_t)nA * 64 + cg2 * 8);
      orow[0] = make_float4(aA[0] * rA, aA[1] * rA, aA[2] * rA, aA[3] * rA);
      orow[1] = make_float4(aA[4] * rA, aA[5] * rA, aA[6] * rA, aA[7] * rA);
    }
    if (nB < N) {
      float4* orow = (float4*)(out + (size_t)nB * 64 + cg2 * 8);
      orow[0] = make_float4(aB[0] * rB, aB[1] * rB, aB[2] * rB, aB[3] * rB);
      orow[1] = make_float4(aB[4] * rB, aB[5] * rB, aB[6] * rB, aB[7] * rB);
    }
  }
}

// ---------------------------------------------------------------------------
extern "C" void kernel_launch(void* const* d_in, const int* in_sizes, int n_in,
                              void* d_out, int out_size, void* d_ws, size_t ws_size,
                              hipStream_t stream) {
  const float* feat  = (const float*)d_in[0];
  const float* W     = (const float*)d_in[1];
  const float* attnl = (const float*)d_in[2];
  const float* attnr = (const float*)d_in[3];
  const int* src = (const int*)d_in[4];
  const int* trg = (const int*)d_in[5];
  float* out = (float*)d_out;

  const int N = in_sizes[0] / 128;  // 100000
  const int E = in_sizes[4];        // 1600000

  const int nbL  = (N + 63) / 64;          // 1563 linear units
  const int nbkt = (N + BN - 1) >> LOGBN;  // 782 buckets of 128 nodes
  const int epb  = (E + NB3 - 1) / NB3;    // 6250 edges per partition

  char* p = (char*)d_ws;
  auto take = [&](size_t bytes) -> char* {
    char* r = p;
    p += (bytes + 255) & ~(size_t)255;
    return r;
  };
  ushort_t* h_bf  = (ushort_t*)take((size_t)N * 64 * 2);   // 12.8 MB
  float* el       = (float*)take((size_t)N * 16);          // 1.6 MB
  float* er       = (float*)take((size_t)N * 16);          // 1.6 MB
  unsigned int* binned = (unsigned int*)take((size_t)E * 4); // 6.4 MB
  int* rowbeg     = (int*)take((size_t)N * 4);             // 0.4 MB
  int* rowend     = (int*)take((size_t)N * 4);             // 0.4 MB
  ushort_t* wfrag = (ushort_t*)take(5 * 4 * 64 * 8 * 2);   // 20.5 KB
  int* blockHist  = (int*)take((size_t)NB3 * nbkt * 4);    // 800 KB
  int* colTotal   = (int*)take((size_t)nbkt * 4);
  int* bucketBase = (int*)take((size_t)(nbkt + 1) * 4);
  float* blockmax2 = (float*)take((size_t)nbL * 2 * 4);
  float* gmaxM    = (float*)take(256);
  int* linCtr     = (int*)take(256);

  // co-residency-safe cooperative grid (multiple of 256, 256..1024 blocks)
  int maxb = 0;
  hipOccupancyMaxActiveBlocksPerMultiprocessor(&maxb, gat_pre, 256, 0);
  if (maxb < 1) maxb = 1;
  if (maxb > 4) maxb = 4;
  const int G = maxb * 256;

  hipMemsetAsync(linCtr, 0, 4, stream);

  void* args[] = {
    (void*)&W, (void*)&attnl, (void*)&attnr, (void*)&wfrag,
    (void*)&src, (void*)&trg, (void*)&E,
    (void*)&nbkt, (void*)&blockHist, (void*)&epb,
    (void*)&feat, (void*)&h_bf, (void*)&el, (void*)&er,
    (void*)&blockmax2, (void*)&N, (void*)&nbL,
    (void*)&colTotal, (void*)&bucketBase, (void*)&binned,
    (void*)&rowbeg, (void*)&rowend, (void*)&gmaxM, (void*)&linCtr
  };
  hipLaunchCooperativeKernel(gat_pre, dim3(G), dim3(256), args, 0, stream);

  gat_agg<<<(N + 15) / 16, 256, 0, stream>>>(binned, rowbeg, rowend,
                                             (const float4*)el,
                                             (const float4*)er, h_bf,
                                             gmaxM, out, N);
}

// Round 14
// 201.790 us; speedup vs baseline: 3.4684x; 3.4684x over previous
//
#include <hip/hip_runtime.h>

typedef unsigned short ushort_t;
typedef __attribute__((ext_vector_type(8))) short bf16x8;
typedef __attribute__((ext_vector_type(4))) float f32x4v;

static __device__ __forceinline__ float bf2f(ushort_t u) {
  union { unsigned int i; float f; } v; v.i = ((unsigned int)u) << 16; return v.f;
}
static __device__ __forceinline__ ushort_t f2bf(float f) {
  union { float f; unsigned int i; } v; v.f = f;
  unsigned int r = v.i + 0x7FFFu + ((v.i >> 16) & 1u);
  return (ushort_t)(r >> 16);
}
static __device__ __forceinline__ float leaky(float s) {
  return s > 0.f ? s : 0.2f * s;
}

// ---------------------------------------------------------------------------
// FUSED: block nb3 packs W_ext into B-fragments; blocks 0..nb3-1 do the
// coarse-bucket histogram. epb is runtime (workspace-sized). [R6 proven]
// ---------------------------------------------------------------------------
__global__ __launch_bounds__(256) void packw_hist(
    const float* __restrict__ W, const float* __restrict__ attnl,
    const float* __restrict__ attnr, ushort_t* __restrict__ wfrag,
    const int* __restrict__ trg, int E, int nbkt,
    int* __restrict__ blockHist, int nb3, int epb)
{
  const int b = blockIdx.x;
  const int t = threadIdx.x;
  if (b == nb3) {
    const int kc = t >> 6, l = t & 63;
    const int q = l >> 4, n = l & 15;
    #pragma unroll
    for (int tile = 0; tile < 5; ++tile) {
      #pragma unroll
      for (int j = 0; j < 8; ++j) {
        const int k = kc * 32 + q * 8 + j;
        float v = 0.f;
        if (tile < 4) {
          v = W[k * 64 + tile * 16 + n];
        } else if (n < 4) {
          for (int f = 0; f < 16; ++f)
            v += W[k * 64 + n * 16 + f] * attnl[n * 16 + f];
        } else if (n < 8) {
          const int hd = n - 4;
          for (int f = 0; f < 16; ++f)
            v += W[k * 64 + hd * 16 + f] * attnr[hd * 16 + f];
        }
        wfrag[((tile * 4 + kc) * 64 + l) * 8 + j] = f2bf(v);
      }
    }
    return;
  }
  __shared__ int hist[256];
  hist[t] = 0;
  __syncthreads();
  const int start = b * epb;
  const int end = min(start + epb, E);
  for (int e = start + t; e < end; e += 256)
    atomicAdd(&hist[trg[e] >> 9], 1);
  __syncthreads();
  if (t < nbkt) blockHist[b * nbkt + t] = hist[t];
}

// ---------------------------------------------------------------------------
// Per-bucket column scan of blockHist -> in-place exclusive prefix + total.
// ---------------------------------------------------------------------------
__global__ __launch_bounds__(64) void bucket_scan(
    int* __restrict__ blockHist, int nb3, int nbkt, int* __restrict__ colTotal)
{
  const int b = blockIdx.x;
  const int l = threadIdx.x;
  int carry = 0;
  for (int r = 0; r * 64 < nb3; ++r) {
    const int i = r * 64 + l;
    int v = (i < nb3) ? blockHist[i * nbkt + b] : 0;
    int incl = v;
    #pragma unroll
    for (int d = 1; d < 64; d <<= 1) {
      int u = __shfl_up(incl, d, 64);
      if (l >= d) incl += u;
    }
    if (i < nb3) blockHist[i * nbkt + b] = carry + incl - v;
    carry += __shfl(incl, 63, 64);
  }
  if (l == 0) colTotal[b] = carry;
}

// ---------------------------------------------------------------------------
// Scan colTotal -> bucketBase; rowoff[N]=E.
// ---------------------------------------------------------------------------
__global__ __launch_bounds__(64) void bucket_base(
    const int* __restrict__ colTotal, int nbkt, int* __restrict__ bucketBase,
    int* __restrict__ rowoff, int N, int E)
{
  const int l = threadIdx.x;
  int carry = 0;
  for (int r = 0; r * 64 < nbkt; ++r) {
    const int i = r * 64 + l;
    int v = (i < nbkt) ? colTotal[i] : 0;
    int incl = v;
    #pragma unroll
    for (int d = 1; d < 64; d <<= 1) {
      int u = __shfl_up(incl, d, 64);
      if (l >= d) incl += u;
    }
    if (i < nbkt) bucketBase[i] = carry + incl - v;
    carry += __shfl(incl, 63, 64);
  }
  if (l == 0) { bucketBase[nbkt] = carry; rowoff[N] = E; }
}

// ---------------------------------------------------------------------------
// Deterministic coarse scatter (no global atomics); payload (src<<9)|localTrg.
// ---------------------------------------------------------------------------
__global__ __launch_bounds__(256) void bucket_scatter(
    const int* __restrict__ src, const int* __restrict__ trg, int E, int nbkt,
    const int* __restrict__ blockHist, const int* __restrict__ bucketBase,
    unsigned int* __restrict__ binned, int epb)
{
  __shared__ int cursor[256];
  const int t = threadIdx.x, b = blockIdx.x;
  if (t < nbkt) cursor[t] = bucketBase[t] + blockHist[b * nbkt + t];
  __syncthreads();
  const int start = b * epb;
  const int end = min(start + epb, E);
  for (int e = start + t; e < end; e += 256) {
    const int ti = trg[e];
    const int bkt = ti >> 9;
    const int pos = atomicAdd(&cursor[bkt], 1);
    binned[pos] = ((unsigned int)src[e] << 9) | (unsigned int)(ti & 511);
  }
}

// ---------------------------------------------------------------------------
// Kernel A (MFMA): h_ext = feat @ W_ext. [R6 proven, unchanged]
// ---------------------------------------------------------------------------
__global__ __launch_bounds__(256) void gat_linear(
    const float* __restrict__ feat, const ushort_t* __restrict__ wfrag,
    ushort_t* __restrict__ h_out, float* __restrict__ el, float* __restrict__ er,
    float* __restrict__ blockmax2, int N)
{
  __shared__ ushort_t sFb[64 * 136];   // 17.4 KB
  __shared__ float wmax[8];
  const int t = threadIdx.x;
  const int b = blockIdx.x;
  const int w = t >> 6, l = t & 63;
  const int q = l >> 4, m = l & 15;

  const float4* gF = (const float4*)(feat + (size_t)b * 64 * 128);
  #pragma unroll
  for (int i = 0; i < 8; ++i) {
    const int idx = i * 256 + t;
    const int node = idx >> 5, off = idx & 31;
    float4 v = make_float4(0.f, 0.f, 0.f, 0.f);
    if (b * 64 + node < N) v = gF[idx];
    unsigned int p0 = ((unsigned int)f2bf(v.y) << 16) | f2bf(v.x);
    unsigned int p1 = ((unsigned int)f2bf(v.w) << 16) | f2bf(v.z);
    *(uint2*)(sFb + node * 136 + off * 4) = make_uint2(p0, p1);
  }
  __syncthreads();

  bf16x8 a[4];
  const ushort_t* arow = sFb + (w * 16 + m) * 136 + q * 8;
  #pragma unroll
  for (int kc = 0; kc < 4; ++kc)
    a[kc] = *(const bf16x8*)(arow + kc * 32);

  #pragma unroll
  for (int tile = 0; tile < 4; ++tile) {
    f32x4v acc = {0.f, 0.f, 0.f, 0.f};
    #pragma unroll
    for (int kc = 0; kc < 4; ++kc) {
      bf16x8 bfr = *(const bf16x8*)(wfrag + ((tile * 4 + kc) * 64 + l) * 8);
      acc = __builtin_amdgcn_mfma_f32_16x16x32_bf16(a[kc], bfr, acc, 0, 0, 0);
    }
    #pragma unroll
    for (int r = 0; r < 4; ++r) {
      const int gn = b * 64 + w * 16 + q * 4 + r;
      if (gn < N) h_out[(size_t)gn * 64 + tile * 16 + m] = f2bf(acc[r]);
    }
  }

  f32x4v acc4 = {0.f, 0.f, 0.f, 0.f};
  #pragma unroll
  for (int kc = 0; kc < 4; ++kc) {
    bf16x8 bfr = *(const bf16x8*)(wfrag + ((4 * 4 + kc) * 64 + l) * 8);
    acc4 = __builtin_amdgcn_mfma_f32_16x16x32_bf16(a[kc], bfr, acc4, 0, 0, 0);
  }
  float mel = -1e30f, mer = -1e30f;
  #pragma unroll
  for (int r = 0; r < 4; ++r) {
    const int gn = b * 64 + w * 16 + q * 4 + r;
    const float v = acc4[r];
    if (m < 4) {
      if (gn < N) el[gn * 4 + m] = v;
      mel = fmaxf(mel, v);
    } else if (m < 8) {
      if (gn < N) er[gn * 4 + (m - 4)] = v;
      mer = fmaxf(mer, v);
    }
  }
  #pragma unroll
  for (int o = 1; o <= 32; o <<= 1) {
    mel = fmaxf(mel, __shfl_xor(mel, o, 64));
    mer = fmaxf(mer, __shfl_xor(mer, o, 64));
  }
  if (l == 0) { wmax[w * 2] = mel; wmax[w * 2 + 1] = mer; }
  __syncthreads();
  if (t == 0) {
    float aa = fmaxf(fmaxf(wmax[0], wmax[2]), fmaxf(wmax[4], wmax[6]));
    float cc = fmaxf(fmaxf(wmax[1], wmax[3]), fmaxf(wmax[5], wmax[7]));
    blockmax2[b * 2] = aa;
    blockmax2[b * 2 + 1] = cc;
  }
}

// ---------------------------------------------------------------------------
// Fine sort (one block per bucket) + block 0 reduces blockmax2 -> gmaxM.
// [R6 proven, unchanged]
// ---------------------------------------------------------------------------
__global__ __launch_bounds__(512) void fine_scatter(
    const unsigned int* __restrict__ binned, const int* __restrict__ bucketBase,
    int* __restrict__ rowoff, int* __restrict__ csrsrc, int N,
    const float* __restrict__ blockmax2, int nbL, float* __restrict__ gmaxM)
{
  __shared__ int cnt[512];
  __shared__ int ws[8];
  __shared__ float wmg[16];
  const int t = threadIdx.x, b = blockIdx.x;
  const int l = t & 63, w = t >> 6;
  const int base = bucketBase[b];
  const int end = bucketBase[b + 1];
  cnt[t] = 0;
  if (b == 0) {
    float mel = -1e30f, mer = -1e30f;
    for (int i = t; i < nbL; i += 512) {
      mel = fmaxf(mel, blockmax2[i * 2]);
      mer = fmaxf(mer, blockmax2[i * 2 + 1]);
    }
    #pragma unroll
    for (int o = 1; o <= 32; o <<= 1) {
      mel = fmaxf(mel, __shfl_xor(mel, o, 64));
      mer = fmaxf(mer, __shfl_xor(mer, o, 64));
    }
    if (l == 0) { wmg[w * 2] = mel; wmg[w * 2 + 1] = mer; }
  }
  __syncthreads();
  if (b == 0 && t == 0) {
    float aa = -1e30f, cc = -1e30f;
    for (int i = 0; i < 8; ++i) {
      aa = fmaxf(aa, wmg[i * 2]);
      cc = fmaxf(cc, wmg[i * 2 + 1]);
    }
    gmaxM[0] = fmaxf(0.f, aa + cc);
  }
  for (int i = base + t; i < end; i += 512)
    atomicAdd(&cnt[binned[i] & 511u], 1);
  __syncthreads();
  const int v = cnt[t];
  int incl = v;
  #pragma unroll
  for (int d = 1; d < 64; d <<= 1) {
    int u = __shfl_up(incl, d, 64);
    if (l >= d) incl += u;
  }
  if (l == 63) ws[w] = incl;
  __syncthreads();
  int woff = 0;
  for (int i = 0; i < w; ++i) woff += ws[i];
  const int loc = woff + incl - v;
  cnt[t] = loc;
  const int gt = b * 512 + t;
  if (gt < N) rowoff[gt] = base + loc;
  __syncthreads();
  for (int i = base + t; i < end; i += 512) {
    const unsigned int pv = binned[i];
    const int lt = (int)(pv & 511u);
    const int pos = base + atomicAdd(&cnt[lt], 1);
    csrsrc[pos] = (int)(pv >> 9);
  }
}

// ---------------------------------------------------------------------------
// Aggregation: FOUR nodes per wave with BATCHED gathers (R11/R12 proven
// inner loop, 44 us) on R6's contiguous rowoff CSR interface.
// ---------------------------------------------------------------------------
#define UNPACK_FMA(hv, p, acc) do { \
  union { unsigned int i; float f; } c_; \
  c_.i = (hv).x << 16;          acc[0] += c_.f * (p); \
  c_.i = (hv).x & 0xffff0000u;  acc[1] += c_.f * (p); \
  c_.i = (hv).y << 16;          acc[2] += c_.f * (p); \
  c_.i = (hv).y & 0xffff0000u;  acc[3] += c_.f * (p); \
  c_.i = (hv).z << 16;          acc[4] += c_.f * (p); \
  c_.i = (hv).z & 0xffff0000u;  acc[5] += c_.f * (p); \
  c_.i = (hv).w << 16;          acc[6] += c_.f * (p); \
  c_.i = (hv).w & 0xffff0000u;  acc[7] += c_.f * (p); \
} while (0)

#define LOADJ(j, hA_, hB_, qA_, qB_) do { \
  const int i_ = iA0 + (j) * 4; \
  const int sA_ = sSw[i_]; \
  const int sB_ = sSw[i_ + 32]; \
  qA_ = sPw[i_ * 4 + hd2]; \
  qB_ = sPw[(i_ + 32) * 4 + hd2]; \
  hA_ = *(const uint4*)(hcg + (size_t)sA_ * 64); \
  hB_ = *(const uint4*)(hcg + (size_t)sB_ * 64); \
} while (0)

__global__ __launch_bounds__(256) void gat_agg(
    const int* __restrict__ csrsrc, const int* __restrict__ rowoff,
    const float4* __restrict__ el4, const float4* __restrict__ er4,
    const ushort_t* __restrict__ hbf, const float* __restrict__ gmaxM,
    float* __restrict__ out, int N)
{
  __shared__ float sP[4 * 64 * 4];
  __shared__ int sS[4 * 64];
  const int t = threadIdx.x;
  const int l = t & 63;
  const int w = t >> 6;
  const int nbase = blockIdx.x * 16 + w * 4;   // this wave's 4 nodes
  const int rg = l >> 3;        // row group 0..7
  const int cg = l & 7;         // col group: feats cg*8..cg*8+7
  const int hd2 = cg >> 1;      // head of those 8 feats
  const int ks = l >> 4;        // staging node 0..3
  const int le = l & 15;        // staging edge slot
  const float M = gmaxM[0];
  float* sPw = sP + w * 256;
  int* sSw = sS + w * 64;
  const ushort_t* hcg = hbf + cg * 8;   // my 16B slice of any row
  const int iA0 = ((rg >> 2) * 16) + (rg & 3);

  const int nk = nbase + ks;
  const int rs = rowoff[min(nk, N)];
  const int re = rowoff[min(nk + 1, N)];
  const float4 ernk = (rs < re) ? er4[nk]
                                : make_float4(0.f, 0.f, 0.f, 0.f);
  int deg = re - rs;
  deg = max(deg, __shfl_xor(deg, 16, 64));
  deg = max(deg, __shfl_xor(deg, 32, 64));   // max degree of the 4 nodes
  const int chunks = (deg + 15) >> 4;

  float aA[8] = {0.f,0.f,0.f,0.f,0.f,0.f,0.f,0.f};
  float aB[8] = {0.f,0.f,0.f,0.f,0.f,0.f,0.f,0.f};
  float dA = 0.f, dB = 0.f;

  for (int c = 0; c < chunks; ++c) {
    int sn = 0;
    float4 pv = make_float4(0.f, 0.f, 0.f, 0.f);
    const int ei = rs + c * 16 + le;
    if (ei < re) {
      sn = csrsrc[ei];
      const float4 a = el4[sn];
      pv.x = __expf(leaky(a.x + ernk.x) - M);
      pv.y = __expf(leaky(a.y + ernk.y) - M);
      pv.z = __expf(leaky(a.z + ernk.z) - M);
      pv.w = __expf(leaky(a.w + ernk.w) - M);
    }
    *(float4*)(sPw + l * 4) = pv;   // pad slots carry p=0
    sSw[l] = sn;                    // pad slots row 0 (valid mem, p=0)

    const int rem = min(deg - c * 16, 16);
    const int jmax = (rem + 3) >> 2;   // wave-uniform: 1..4
    uint4 h0A, h0B, h1A, h1B, h2A, h2B, h3A, h3B;
    float q0A, q0B, q1A, q1B, q2A, q2B, q3A, q3B;
    LOADJ(0, h0A, h0B, q0A, q0B);
    if (jmax > 1) LOADJ(1, h1A, h1B, q1A, q1B);
    if (jmax > 2) LOADJ(2, h2A, h2B, q2A, q2B);
    if (jmax > 3) LOADJ(3, h3A, h3B, q3A, q3B);

    UNPACK_FMA(h0A, q0A, aA); UNPACK_FMA(h0B, q0B, aB);
    dA += q0A; dB += q0B;
    if (jmax > 1) {
      UNPACK_FMA(h1A, q1A, aA); UNPACK_FMA(h1B, q1B, aB);
      dA += q1A; dB += q1B;
    }
    if (jmax > 2) {
      UNPACK_FMA(h2A, q2A, aA); UNPACK_FMA(h2B, q2B, aB);
      dA += q2A; dB += q2B;
    }
    if (jmax > 3) {
      UNPACK_FMA(h3A, q3A, aA); UNPACK_FMA(h3B, q3B, aB);
      dA += q3A; dB += q3B;
    }
  }

  #pragma unroll
  for (int o = 8; o <= 16; o <<= 1) {
    #pragma unroll
    for (int i = 0; i < 8; ++i) {
      aA[i] += __shfl_xor(aA[i], o, 64);
      aB[i] += __shfl_xor(aB[i], o, 64);
    }
    dA += __shfl_xor(dA, o, 64);
    dB += __shfl_xor(dB, o, 64);
  }
  if ((rg & 3) == 0) {
    const int nA = nbase + (rg >> 2);
    const int nB = nA + 2;
    const float rA = 1.0f / (dA + 1e-16f);
    const float rB = 1.0f / (dB + 1e-16f);
    if (nA < N) {
      float4* orow = (float4*)(out + (size_t)nA * 64 + cg * 8);
      orow[0] = make_float4(aA[0] * rA, aA[1] * rA, aA[2] * rA, aA[3] * rA);
      orow[1] = make_float4(aA[4] * rA, aA[5] * rA, aA[6] * rA, aA[7] * rA);
    }
    if (nB < N) {
      float4* orow = (float4*)(out + (size_t)nB * 64 + cg * 8);
      orow[0] = make_float4(aB[0] * rB, aB[1] * rB, aB[2] * rB, aB[3] * rB);
      orow[1] = make_float4(aB[4] * rB, aB[5] * rB, aB[6] * rB, aB[7] * rB);
    }
  }
}

// ---------------------------------------------------------------------------
extern "C" void kernel_launch(void* const* d_in, const int* in_sizes, int n_in,
                              void* d_out, int out_size, void* d_ws, size_t ws_size,
                              hipStream_t stream) {
  const float* feat  = (const float*)d_in[0];
  const float* W     = (const float*)d_in[1];
  const float* attnl = (const float*)d_in[2];
  const float* attnr = (const float*)d_in[3];
  const int* src = (const int*)d_in[4];
  const int* trg = (const int*)d_in[5];
  float* out = (float*)d_out;

  const int N = in_sizes[0] / 128;  // 100000
  const int E = in_sizes[4];        // 1600000

  const int nbL  = (N + 63) / 64;        // 1563 linear blocks
  const int nbkt = (N + 511) >> 9;       // 196 coarse buckets

  char* p = (char*)d_ws;
  auto take = [&](size_t bytes) -> char* {
    char* r = p;
    p += (bytes + 255) & ~(size_t)255;
    return r;
  };
  // fixed buffers first, then size blockHist to whatever space remains
  ushort_t* h_bf  = (ushort_t*)take((size_t)N * 64 * 2); // 12.8 MB
  float* el       = (float*)take((size_t)N * 16);        // 1.6 MB
  float* er       = (float*)take((size_t)N * 16);        // 1.6 MB
  int* rowoff     = (int*)take((size_t)(N + 1) * 4);
  int* csrsrc     = (int*)take((size_t)E * 4);           // 6.4 MB
  unsigned int* binned = (unsigned int*)take((size_t)E * 4); // 6.4 MB
  ushort_t* wfrag = (ushort_t*)take(5 * 4 * 64 * 8 * 2); // 20.5 KB
  int* colTotal   = (int*)take((size_t)nbkt * 4);
  int* bucketBase = (int*)take((size_t)(nbkt + 1) * 4);
  float* blockmax2 = (float*)take((size_t)nbL * 2 * 4);
  float* gmaxM    = (float*)take(256);

  // workspace-safe sort-block count: target 800 blocks (fills 256 CUs),
  // degrade gracefully toward the proven ~200-block config if ws is tight
  const size_t used = (size_t)(p - (char*)d_ws);
  const size_t avail = (ws_size > used + 512) ? (ws_size - used - 512) : 0;
  int nb3 = (int)(avail / ((size_t)nbkt * 4));
  if (nb3 > 800) nb3 = 800;
  if (nb3 < 64) nb3 = 64;
  int epb = (E + nb3 - 1) / nb3;
  nb3 = (E + epb - 1) / epb;             // drop empty tail blocks
  int* blockHist  = (int*)take((size_t)nb3 * nbkt * 4);

  packw_hist<<<nb3 + 1, 256, 0, stream>>>(W, attnl, attnr, wfrag,
                                          trg, E, nbkt, blockHist, nb3, epb);
  bucket_scan<<<nbkt, 64, 0, stream>>>(blockHist, nb3, nbkt, colTotal);
  bucket_base<<<1, 64, 0, stream>>>(colTotal, nbkt, bucketBase, rowoff, N, E);
  bucket_scatter<<<nb3, 256, 0, stream>>>(src, trg, E, nbkt, blockHist,
                                          bucketBase, binned, epb);
  gat_linear<<<nbL, 256, 0, stream>>>(feat, wfrag, h_bf, el, er,
                                      blockmax2, N);
  fine_scatter<<<nbkt, 512, 0, stream>>>(binned, bucketBase, rowoff, csrsrc,
                                         N, blockmax2, nbL, gmaxM);
  gat_agg<<<(N + 15) / 16, 256, 0, stream>>>(csrsrc, rowoff, (const float4*)el,
                                             (const float4*)er, h_bf,
                                             gmaxM, out, N);
}